// Round 6
// baseline (340.469 us; speedup 1.0000x reference)
//
#include <hip/hip_runtime.h>
#include <hip/hip_bf16.h>
#include <stdint.h>

typedef __hip_bfloat16 bf16;
typedef __attribute__((ext_vector_type(8))) short short8;
typedef __attribute__((ext_vector_type(4))) float f32x4;

#define NTOK  4096      // B*T
#define EDIM  1024
#define NEXPT 8
#define INTERD 1408
#define MAXP  4096
#define WELEM (NEXPT * INTERD * EDIM)

// async global->LDS, 16B per lane, dest = wave-uniform base + lane*16
#define GL16(g, l) __builtin_amdgcn_global_load_lds( \
    (const __attribute__((address_space(1))) unsigned int*)(g), \
    (__attribute__((address_space(3))) unsigned int*)(l), 16, 0, 0)

#define WAIT_VM(n)   asm volatile("s_waitcnt vmcnt(" #n ")" ::: "memory")
#define BAR()        __builtin_amdgcn_s_barrier()
#define PRIO(n)      __builtin_amdgcn_s_setprio(n)

// ---------------- fp32 -> bf16 conversion for the 3 weight tensors ----------------
__global__ __launch_bounds__(256) void cvt3_kernel(const float* __restrict__ wg, bf16* __restrict__ wgb,
                                                   const float* __restrict__ wu, bf16* __restrict__ wub,
                                                   const float* __restrict__ wd, bf16* __restrict__ wdb) {
    const float* src; bf16* dst; int b = blockIdx.x;
    if (b < 1024)      { src = wg; dst = wgb; }
    else if (b < 2048) { src = wu; dst = wub; b -= 1024; }
    else               { src = wd; dst = wdb; b -= 2048; }
    int n = WELEM;
    int i = (b * 256 + threadIdx.x) * 4;
    int stride = 1024 * 256 * 4;
    for (; i < n; i += stride) {
        float4 v = *(const float4*)(src + i);
        ushort4 o; bf16 t;
        t = __float2bfloat16(v.x); o.x = *(unsigned short*)&t;
        t = __float2bfloat16(v.y); o.y = *(unsigned short*)&t;
        t = __float2bfloat16(v.z); o.z = *(unsigned short*)&t;
        t = __float2bfloat16(v.w); o.w = *(unsigned short*)&t;
        *(ushort4*)(dst + i) = o;
    }
}

// ------- router: top2 softmax, bucket scatter + inverse map + x->bf16 fused ---------
__global__ __launch_bounds__(64) void router_kernel(const float* __restrict__ x,
                                                    const float* __restrict__ gw,
                                                    bf16* __restrict__ xb,
                                                    int* __restrict__ counts,
                                                    int* __restrict__ ptok,
                                                    float* __restrict__ pprob,
                                                    int* __restrict__ inv) {
    int t = blockIdx.x;
    int lane = threadIdx.x;
    const float* xr = x + (size_t)t * EDIM;
    double acc[NEXPT];
#pragma unroll
    for (int e = 0; e < NEXPT; e++) acc[e] = 0.0;
    for (int d = lane; d < EDIM; d += 64) {
        float xv = xr[d];
#pragma unroll
        for (int e = 0; e < NEXPT; e++) acc[e] += (double)xv * (double)gw[e * EDIM + d];
    }
    // fused x -> bf16 (row is hot in L1)
    bf16* xbr = xb + (size_t)t * EDIM;
#pragma unroll
    for (int j = 0; j < 4; j++) {
        float4 v = *(const float4*)(xr + lane * 16 + j * 4);
        ushort4 o; bf16 c;
        c = __float2bfloat16(v.x); o.x = *(unsigned short*)&c;
        c = __float2bfloat16(v.y); o.y = *(unsigned short*)&c;
        c = __float2bfloat16(v.z); o.z = *(unsigned short*)&c;
        c = __float2bfloat16(v.w); o.w = *(unsigned short*)&c;
        *(ushort4*)(xbr + lane * 16 + j * 4) = o;
    }
#pragma unroll
    for (int off = 32; off >= 1; off >>= 1) {
#pragma unroll
        for (int e = 0; e < NEXPT; e++) acc[e] += __shfl_xor(acc[e], off, 64);
    }
    if (lane == 0) {
        int e0 = 0; double s0 = acc[0];
        for (int e = 1; e < NEXPT; e++) if (acc[e] > s0) { s0 = acc[e]; e0 = e; }
        int e1 = -1; double s1 = -1e300;
        for (int e = 0; e < NEXPT; e++) if (e != e0 && acc[e] > s1) { s1 = acc[e]; e1 = e; }
        float z = __expf((float)(s1 - s0));
        float p0 = 1.f / (1.f + z);
        float p1 = 1.f - p0;
        int pos0 = atomicAdd(&counts[e0], 1);
        ptok[e0 * MAXP + pos0] = t; pprob[e0 * MAXP + pos0] = p0;
        int pos1 = atomicAdd(&counts[e1], 1);
        ptok[e1 * MAXP + pos1] = t; pprob[e1 * MAXP + pos1] = p1;
        inv[2 * t]     = (e0 << 16) | pos0;
        inv[2 * t + 1] = (e1 << 16) | pos1;
    }
}

__global__ void scan_kernel(const int* __restrict__ counts, int* __restrict__ offsets) {
    if (threadIdx.x == 0 && blockIdx.x == 0) {
        int s = 0;
        for (int e = 0; e < NEXPT; e++) { offsets[e] = s; s += counts[e]; }
    }
}

// ======================= GEMM1: h = p * silu(x@wg^T) * (x@wu^T) =======================
// Tile 256tok x 128inter, BK=64, 16 K-tiles. 8 waves (4M x 2N), wave-tile 64x64 on BOTH
// g and u (accg/accu 4x4). 2-deep LDS (A 32K + G 16K + U 16K = 64KB x2 = 128KB).
// 2 phases/K-tile: {stage AG(t+1); vm(6); BAR; a+g reads; 32 MFMA; BAR}
//                  {stage U(t+1); u reads; 32 MFMA; BAR}. Counted vmcnt, T2 swizzle.
// grid: bx = e + 8*(mt + 4*nt), mt<4, nt<11 -> 352 blocks; expert->XCD affinity.
__global__ __launch_bounds__(512, 2) void gemm1_kernel(const bf16* __restrict__ xb,
                                                       const bf16* __restrict__ wgb,
                                                       const bf16* __restrict__ wub,
                                                       bf16* __restrict__ hout,
                                                       const int* __restrict__ counts,
                                                       const int* __restrict__ offsets,
                                                       const int* __restrict__ ptok,
                                                       const float* __restrict__ pprob) {
    int bx = blockIdx.x;
    int e  = bx & 7;
    int mt = (bx >> 3) & 3;
    int nt = bx >> 5;                 // 0..10
    int cnt = counts[e];
    int n0 = nt * 128;
    int hbase = offsets[e];

    // per buf: A [256][64] @0 (16384 el), G [128][64] @16384, U [128][64] @24576
    __shared__ __align__(16) bf16 smem[2 * 32768];

    int tid  = threadIdx.x;
    int lane = tid & 63;
    int wid  = tid >> 6;
    int wm   = wid >> 1;              // 0..3  (64-tok stripe)
    int wn   = wid & 1;               // 0..1  (64-inter stripe)

    int srow = lane >> 3;                      // 0..7
    int qs   = ((lane & 7) ^ srow) * 8;        // swizzled SOURCE elem offset in 64-el row
    int l15  = lane & 15;
    int l4   = lane >> 4;                      // 0..3
    int rx   = lane & 7;                       // read-side XOR
    int rbw  = wid * 8 + srow;                 // staging row 0..63

    const bf16* gGr = wgb + ((size_t)e * INTERD + n0) * EDIM;
    const bf16* gUr = wub + ((size_t)e * INTERD + n0) * EDIM;
    const bf16* gG0 = gGr + (size_t)rbw * EDIM + qs;
    const bf16* gG1 = gGr + (size_t)(64 + rbw) * EDIM + qs;
    const bf16* gU0 = gUr + (size_t)rbw * EDIM + qs;
    const bf16* gU1 = gUr + (size_t)(64 + rbw) * EDIM + qs;

    for (int m0 = mt * 256; m0 < cnt; m0 += 1024) {
        WAIT_VM(0);                   // clean vmcnt across m0 iterations
        const bf16* gA0 = xb + (size_t)ptok[e * MAXP + min(m0 +       rbw, cnt - 1)] * EDIM + qs;
        const bf16* gA1 = xb + (size_t)ptok[e * MAXP + min(m0 +  64 + rbw, cnt - 1)] * EDIM + qs;
        const bf16* gA2 = xb + (size_t)ptok[e * MAXP + min(m0 + 128 + rbw, cnt - 1)] * EDIM + qs;
        const bf16* gA3 = xb + (size_t)ptok[e * MAXP + min(m0 + 192 + rbw, cnt - 1)] * EDIM + qs;

        f32x4 accg[4][4], accu[4][4];
#pragma unroll
        for (int m = 0; m < 4; m++)
#pragma unroll
            for (int n = 0; n < 4; n++) {
                accg[m][n] = (f32x4){0.f, 0.f, 0.f, 0.f};
                accu[m][n] = (f32x4){0.f, 0.f, 0.f, 0.f};
            }

#define SB1(t) (smem + ((t) & 1) * 32768)
#define G1_STAGE_AG(t) do { bf16* sb_ = SB1(t); int ko_ = (t) * 64; \
        GL16(gA0 + ko_, sb_ + (wid * 8) * 64); \
        GL16(gA1 + ko_, sb_ + (64 + wid * 8) * 64); \
        GL16(gA2 + ko_, sb_ + (128 + wid * 8) * 64); \
        GL16(gA3 + ko_, sb_ + (192 + wid * 8) * 64); \
        GL16(gG0 + ko_, sb_ + 16384 + (wid * 8) * 64); \
        GL16(gG1 + ko_, sb_ + 16384 + (64 + wid * 8) * 64); } while (0)
#define G1_STAGE_U(t) do { bf16* sb_ = SB1(t); int ko_ = (t) * 64; \
        GL16(gU0 + ko_, sb_ + 24576 + (wid * 8) * 64); \
        GL16(gU1 + ko_, sb_ + 24576 + (64 + wid * 8) * 64); } while (0)

        G1_STAGE_AG(0); G1_STAGE_U(0);     // prologue: tile 0 (8 loads in flight)

        for (int t = 0; t < 16; ++t) {
            const bf16* sb = SB1(t);
            // ---- phase 1: A+G of tile t ----
            if (t + 1 < 16) { G1_STAGE_AG(t + 1); WAIT_VM(6); }
            else            { WAIT_VM(0); }
            BAR();                                 // tile t fully visible
            short8 a_[4][2], gf[4][2];
#pragma unroll
            for (int m = 0; m < 4; m++)
#pragma unroll
                for (int kh = 0; kh < 2; kh++)
                    a_[m][kh] = *(const short8*)&sb[(wm * 64 + m * 16 + l15) * 64 +
                                                    (((kh * 4 + l4) ^ rx) * 8)];
#pragma unroll
            for (int n = 0; n < 4; n++)
#pragma unroll
                for (int kh = 0; kh < 2; kh++)
                    gf[n][kh] = *(const short8*)&sb[16384 + (wn * 64 + n * 16 + l15) * 64 +
                                                    (((kh * 4 + l4) ^ rx) * 8)];
            PRIO(1);
#pragma unroll
            for (int m = 0; m < 4; m++)
#pragma unroll
                for (int n = 0; n < 4; n++)
#pragma unroll
                    for (int kh = 0; kh < 2; kh++)
                        accg[m][n] = __builtin_amdgcn_mfma_f32_16x16x32_bf16(
                            a_[m][kh], gf[n][kh], accg[m][n], 0, 0, 0);
            PRIO(0);
            BAR();
            // ---- phase 2: U of tile t ----
            if (t + 1 < 16) G1_STAGE_U(t + 1);
            short8 uf[4][2];
#pragma unroll
            for (int n = 0; n < 4; n++)
#pragma unroll
                for (int kh = 0; kh < 2; kh++)
                    uf[n][kh] = *(const short8*)&sb[24576 + (wn * 64 + n * 16 + l15) * 64 +
                                                    (((kh * 4 + l4) ^ rx) * 8)];
            PRIO(1);
#pragma unroll
            for (int m = 0; m < 4; m++)
#pragma unroll
                for (int n = 0; n < 4; n++)
#pragma unroll
                    for (int kh = 0; kh < 2; kh++)
                        accu[m][n] = __builtin_amdgcn_mfma_f32_16x16x32_bf16(
                            a_[m][kh], uf[n][kh], accu[m][n], 0, 0, 0);
            PRIO(0);
            BAR();
        }
#undef SB1
#undef G1_STAGE_AG
#undef G1_STAGE_U

        // epilogue: h = silu(g) * u * p
#pragma unroll
        for (int m = 0; m < 4; m++)
#pragma unroll
            for (int n = 0; n < 4; n++)
#pragma unroll
                for (int r = 0; r < 4; r++) {
                    int pos = m0 + wm * 64 + m * 16 + l4 * 4 + r;
                    if (pos < cnt) {
                        int col = n0 + wn * 64 + n * 16 + l15;
                        float p = pprob[e * MAXP + pos];
                        float gv = accg[m][n][r];
                        float uv = accu[m][n][r];
                        float hv = (gv / (1.f + __expf(-gv))) * uv * p;
                        hout[(size_t)(hbase + pos) * INTERD + col] = __float2bfloat16(hv);
                    }
                }
    }
}

// ======================= GEMM2: out2[slot] = h[slot] @ wd[e]^T =======================
// Tile 256slot x 128col, BK=64, 22 K-tiles. 8 waves (2M x 4N), wave = 128x32.
// 3-deep pipeline, 2 phases/K-tile (m-half 0, m-half 1), vmcnt(10), swizzle.
// grid: bx = e + 8*(mt + 4*nt), mt<4, nt<8 -> 256 blocks (one full round).
__global__ __launch_bounds__(512, 2) void gemm2_kernel(const bf16* __restrict__ h,
                                                       const bf16* __restrict__ wdb,
                                                       float* __restrict__ out2,
                                                       const int* __restrict__ counts,
                                                       const int* __restrict__ offsets) {
    int bx = blockIdx.x;
    int e  = bx & 7;
    int mt = (bx >> 3) & 3;
    int nt = bx >> 5;                 // 0..7
    int cnt = counts[e];
    int n0 = nt * 128;
    int hbase = offsets[e];

    __shared__ __align__(16) bf16 smem[3 * 24576];

    int tid  = threadIdx.x;
    int lane = tid & 63;
    int wid  = tid >> 6;
    int wm   = wid >> 2;              // 0..1 (128-row half)
    int wn   = wid & 3;               // 0..3 (32-col slice)

    int srow = lane >> 3;
    int qs   = ((lane & 7) ^ srow) * 8;
    int l15  = lane & 15;
    int l4   = lane >> 4;
    int rx   = lane & 7;
    int rbw  = wid * 8 + srow;        // staging row 0..63

    const bf16* gB0 = wdb + ((size_t)e * EDIM + n0 + rbw) * INTERD + qs;
    const bf16* gB1 = wdb + ((size_t)e * EDIM + n0 + 64 + rbw) * INTERD + qs;

    for (int m0 = mt * 256; m0 < cnt; m0 += 1024) {
        WAIT_VM(0);
        const bf16* gA0 = h + (size_t)(hbase + min(m0 + rbw,       cnt - 1)) * INTERD + qs;
        const bf16* gA1 = h + (size_t)(hbase + min(m0 + 64 + rbw,  cnt - 1)) * INTERD + qs;
        const bf16* gA2 = h + (size_t)(hbase + min(m0 + 128 + rbw, cnt - 1)) * INTERD + qs;
        const bf16* gA3 = h + (size_t)(hbase + min(m0 + 192 + rbw, cnt - 1)) * INTERD + qs;

        f32x4 acc[8][2];
#pragma unroll
        for (int m = 0; m < 8; m++)
#pragma unroll
            for (int n = 0; n < 2; n++) acc[m][n] = (f32x4){0.f, 0.f, 0.f, 0.f};

#define SB2(t) (smem + ((t) % 3) * 24576)
#define G2_STAGE_A(t) do { bf16* sb_ = SB2(t); int ko_ = (t) * 64; \
        GL16(gA0 + ko_, sb_ + (wid * 8) * 64); \
        GL16(gA1 + ko_, sb_ + (64 + wid * 8) * 64); \
        GL16(gA2 + ko_, sb_ + (128 + wid * 8) * 64); \
        GL16(gA3 + ko_, sb_ + (192 + wid * 8) * 64); } while (0)
#define G2_STAGE_B(t) do { bf16* sb_ = SB2(t); int ko_ = (t) * 64; \
        GL16(gB0 + ko_, sb_ + 16384 + (wid * 8) * 64); \
        GL16(gB1 + ko_, sb_ + 16384 + (64 + wid * 8) * 64); } while (0)

        G2_STAGE_A(0); G2_STAGE_B(0);
        G2_STAGE_A(1); G2_STAGE_B(1);

        for (int t = 0; t < 22; ++t) {
            const bf16* sb = SB2(t);
            // ---- phase 1 (m-half 0) ----
            if (t + 2 < 22)       { G2_STAGE_A(t + 2); WAIT_VM(10); }
            else if (t + 2 == 22) { WAIT_VM(6); }
            else                  { WAIT_VM(0); }
            BAR();
            short8 a_[4][2], bf_[2][2];
#pragma unroll
            for (int m = 0; m < 4; m++)
#pragma unroll
                for (int kh = 0; kh < 2; kh++)
                    a_[m][kh] = *(const short8*)&sb[(wm * 128 + m * 16 + l15) * 64 +
                                                    (((kh * 4 + l4) ^ rx) * 8)];
#pragma unroll
            for (int n = 0; n < 2; n++)
#pragma unroll
                for (int kh = 0; kh < 2; kh++)
                    bf_[n][kh] = *(const short8*)&sb[16384 + (wn * 32 + n * 16 + l15) * 64 +
                                                     (((kh * 4 + l4) ^ rx) * 8)];
            PRIO(1);
#pragma unroll
            for (int m = 0; m < 4; m++)
#pragma unroll
                for (int n = 0; n < 2; n++)
#pragma unroll
                    for (int kh = 0; kh < 2; kh++)
                        acc[m][n] = __builtin_amdgcn_mfma_f32_16x16x32_bf16(
                            a_[m][kh], bf_[n][kh], acc[m][n], 0, 0, 0);
            PRIO(0);
            BAR();
            // ---- phase 2 (m-half 1) ----
            if (t + 2 < 22) G2_STAGE_B(t + 2);
            short8 a2_[4][2];
#pragma unroll
            for (int m = 0; m < 4; m++)
#pragma unroll
                for (int kh = 0; kh < 2; kh++)
                    a2_[m][kh] = *(const short8*)&sb[(wm * 128 + 64 + m * 16 + l15) * 64 +
                                                     (((kh * 4 + l4) ^ rx) * 8)];
            PRIO(1);
#pragma unroll
            for (int m = 0; m < 4; m++)
#pragma unroll
                for (int n = 0; n < 2; n++)
#pragma unroll
                    for (int kh = 0; kh < 2; kh++)
                        acc[4 + m][n] = __builtin_amdgcn_mfma_f32_16x16x32_bf16(
                            a2_[m][kh], bf_[n][kh], acc[4 + m][n], 0, 0, 0);
            PRIO(0);
            BAR();
        }
#undef SB2
#undef G2_STAGE_A
#undef G2_STAGE_B

#pragma unroll
        for (int m = 0; m < 8; m++)
#pragma unroll
            for (int n = 0; n < 2; n++)
#pragma unroll
                for (int r = 0; r < 4; r++) {
                    int pos = m0 + wm * 128 + (m >> 2) * 64 + (m & 3) * 16 + l4 * 4 + r;
                    if (pos < cnt) {
                        int col = n0 + wn * 32 + n * 16 + l15;
                        out2[(size_t)(hbase + pos) * EDIM + col] = acc[m][n][r];
                    }
                }
    }
}

// ---------------- combine: y[t] = out2[slot0] + out2[slot1] (probs already folded) ---
__global__ __launch_bounds__(256) void combine_kernel(const float* __restrict__ out2,
                                                      const int* __restrict__ inv,
                                                      const int* __restrict__ offsets,
                                                      float* __restrict__ y) {
    int idx = blockIdx.x * 256 + threadIdx.x;   // NTOK*EDIM/4 threads
    int t = idx >> 8;
    int c = (idx & 255) * 4;
    int a = inv[2 * t], b = inv[2 * t + 1];
    size_t sa = (size_t)(offsets[a >> 16] + (a & 0xFFFF)) * EDIM + c;
    size_t sb = (size_t)(offsets[b >> 16] + (b & 0xFFFF)) * EDIM + c;
    float4 va = *(const float4*)(out2 + sa);
    float4 vb = *(const float4*)(out2 + sb);
    float4 o;
    o.x = va.x + vb.x; o.y = va.y + vb.y; o.z = va.z + vb.z; o.w = va.w + vb.w;
    *(float4*)(y + (size_t)t * EDIM + c) = o;
}

// ---------------- launch ----------------
extern "C" void kernel_launch(void* const* d_in, const int* in_sizes, int n_in,
                              void* d_out, int out_size, void* d_ws, size_t ws_size,
                              hipStream_t stream) {
    const float* x      = (const float*)d_in[0];
    const float* gate_w = (const float*)d_in[1];
    const float* wg     = (const float*)d_in[2];
    const float* wu     = (const float*)d_in[3];
    const float* wd     = (const float*)d_in[4];
    float* y = (float*)d_out;

    char* ws = (char*)d_ws;
    constexpr size_t SZ_XB = (size_t)NTOK * EDIM * 2;          // 8 MB
    constexpr size_t SZ_W  = (size_t)WELEM * 2;                // 23.07 MB
    constexpr size_t SZ_H  = (size_t)NTOK * 2 * INTERD * 2;    // 23.07 MB
    bf16* xb  = (bf16*)ws;
    bf16* wgb = (bf16*)(ws + SZ_XB);
    bf16* wub = (bf16*)(ws + SZ_XB + SZ_W);
    bf16* wdb = (bf16*)(ws + SZ_XB + 2 * SZ_W);
    bf16* h   = (bf16*)(ws + SZ_XB + 3 * SZ_W);
    char* meta = ws + SZ_XB + 3 * SZ_W + SZ_H;
    int*   counts  = (int*)meta;
    int*   offsets = (int*)(meta + 256);
    int*   ptok    = (int*)(meta + 512);
    float* pprob   = (float*)(meta + 512 + (size_t)NEXPT * MAXP * 4);
    int*   inv     = (int*)(meta + 512 + (size_t)NEXPT * MAXP * 8);
    // out2 (8192*1024*4 = 33.6 MB) aliases wgb+wub (46.1 MB), dead after gemm1
    float* out2 = (float*)(ws + SZ_XB);

    hipMemsetAsync(counts, 0, 256, stream);

    cvt3_kernel<<<3072, 256, 0, stream>>>(wg, wgb, wu, wub, wd, wdb);
    router_kernel<<<NTOK, 64, 0, stream>>>(x, gate_w, xb, counts, ptok, pprob, inv);
    scan_kernel<<<1, 64, 0, stream>>>(counts, offsets);

    // bx = e + 8*(mt + 4*nt): expert -> XCD affinity via round-robin
    gemm1_kernel<<<NEXPT * 4 * (INTERD / 128), 512, 0, stream>>>(
        xb, wgb, wub, h, counts, offsets, ptok, pprob);
    gemm2_kernel<<<NEXPT * 4 * (EDIM / 128), 512, 0, stream>>>(
        h, wdb, out2, counts, offsets);
    combine_kernel<<<NTOK * EDIM / 4 / 256, 256, 0, stream>>>(out2, inv, offsets, y);
}

// Round 8
// 279.720 us; speedup vs baseline: 1.2172x; 1.2172x over previous
//
#include <hip/hip_runtime.h>
#include <hip/hip_bf16.h>
#include <stdint.h>

typedef __hip_bfloat16 bf16;
typedef __attribute__((ext_vector_type(8))) short short8;
typedef __attribute__((ext_vector_type(4))) float f32x4;

#define NTOK  4096      // B*T
#define EDIM  1024
#define NEXPT 8
#define INTERD 1408
#define MAXP  4096
#define WELEM (NEXPT * INTERD * EDIM)

// async global->LDS, 16B per lane, dest = wave-uniform base + lane*16 (LINEAR)
#define GL16(g, l) __builtin_amdgcn_global_load_lds( \
    (const __attribute__((address_space(1))) unsigned int*)(g), \
    (__attribute__((address_space(3))) unsigned int*)(l), 16, 0, 0)

#define WAIT_VM(n)   asm volatile("s_waitcnt vmcnt(" #n ")" ::: "memory")
#define BAR()        __builtin_amdgcn_s_barrier()
#define PRIO(n)      __builtin_amdgcn_s_setprio(n)

// ---------------- fp32 -> bf16 conversion for the 3 weight tensors ----------------
__global__ __launch_bounds__(256) void cvt3_kernel(const float* __restrict__ wg, bf16* __restrict__ wgb,
                                                   const float* __restrict__ wu, bf16* __restrict__ wub,
                                                   const float* __restrict__ wd, bf16* __restrict__ wdb) {
    const float* src; bf16* dst; int b = blockIdx.x;
    if (b < 1024)      { src = wg; dst = wgb; }
    else if (b < 2048) { src = wu; dst = wub; b -= 1024; }
    else               { src = wd; dst = wdb; b -= 2048; }
    int n = WELEM;
    int i = (b * 256 + threadIdx.x) * 4;
    int stride = 1024 * 256 * 4;
    for (; i < n; i += stride) {
        float4 v = *(const float4*)(src + i);
        ushort4 o; bf16 t;
        t = __float2bfloat16(v.x); o.x = *(unsigned short*)&t;
        t = __float2bfloat16(v.y); o.y = *(unsigned short*)&t;
        t = __float2bfloat16(v.z); o.z = *(unsigned short*)&t;
        t = __float2bfloat16(v.w); o.w = *(unsigned short*)&t;
        *(ushort4*)(dst + i) = o;
    }
}

// ------- router: top2 softmax, bucket scatter + inverse map + x->bf16 fused ---------
__global__ __launch_bounds__(64) void router_kernel(const float* __restrict__ x,
                                                    const float* __restrict__ gw,
                                                    bf16* __restrict__ xb,
                                                    int* __restrict__ counts,
                                                    int* __restrict__ ptok,
                                                    float* __restrict__ pprob,
                                                    int* __restrict__ inv) {
    int t = blockIdx.x;
    int lane = threadIdx.x;
    const float* xr = x + (size_t)t * EDIM;
    double acc[NEXPT];
#pragma unroll
    for (int e = 0; e < NEXPT; e++) acc[e] = 0.0;
    for (int d = lane; d < EDIM; d += 64) {
        float xv = xr[d];
#pragma unroll
        for (int e = 0; e < NEXPT; e++) acc[e] += (double)xv * (double)gw[e * EDIM + d];
    }
    // fused x -> bf16 (row is hot in L1)
    bf16* xbr = xb + (size_t)t * EDIM;
#pragma unroll
    for (int j = 0; j < 4; j++) {
        float4 v = *(const float4*)(xr + lane * 16 + j * 4);
        ushort4 o; bf16 c;
        c = __float2bfloat16(v.x); o.x = *(unsigned short*)&c;
        c = __float2bfloat16(v.y); o.y = *(unsigned short*)&c;
        c = __float2bfloat16(v.z); o.z = *(unsigned short*)&c;
        c = __float2bfloat16(v.w); o.w = *(unsigned short*)&c;
        *(ushort4*)(xbr + lane * 16 + j * 4) = o;
    }
#pragma unroll
    for (int off = 32; off >= 1; off >>= 1) {
#pragma unroll
        for (int e = 0; e < NEXPT; e++) acc[e] += __shfl_xor(acc[e], off, 64);
    }
    if (lane == 0) {
        int e0 = 0; double s0 = acc[0];
        for (int e = 1; e < NEXPT; e++) if (acc[e] > s0) { s0 = acc[e]; e0 = e; }
        int e1 = -1; double s1 = -1e300;
        for (int e = 0; e < NEXPT; e++) if (e != e0 && acc[e] > s1) { s1 = acc[e]; e1 = e; }
        float z = __expf((float)(s1 - s0));
        float p0 = 1.f / (1.f + z);
        float p1 = 1.f - p0;
        int pos0 = atomicAdd(&counts[e0], 1);
        ptok[e0 * MAXP + pos0] = t; pprob[e0 * MAXP + pos0] = p0;
        int pos1 = atomicAdd(&counts[e1], 1);
        ptok[e1 * MAXP + pos1] = t; pprob[e1 * MAXP + pos1] = p1;
        inv[2 * t]     = (e0 << 16) | pos0;
        inv[2 * t + 1] = (e1 << 16) | pos1;
    }
}

__global__ void scan_kernel(const int* __restrict__ counts, int* __restrict__ offsets,
                            int* __restrict__ wq) {
    if (threadIdx.x == 0 && blockIdx.x == 0) {
        int s = 0;
        for (int e = 0; e < NEXPT; e++) { offsets[e] = s; s += counts[e]; wq[e] = 0; }
    }
}

// ======================= GEMM1: h = p * silu(x@wg^T) * (x@wu^T) =======================
// Tile 128tok x 128inter, BK=32, 32 K-tiles. 8 waves (2M x 4N), wave 64x32 on g AND u.
// LDS: per slot A[128][32]+G[128][32]+U[128][32] = 24KB, 3-slot ring = 72KB
//   -> 2 blocks/CU (16 waves/CU) for cross-block latency hiding.
// Prefetch 2 tiles ahead, counted vmcnt(6). 2-bit XOR swizzle (src+read, linear dest).
// Work: dynamic per-expert queue, claimed ONCE PER BLOCK (tid 0) and broadcast.
// grid 512 blocks, bx&7 = expert -> XCD affinity; mt-fastest order for L2 reuse.
__global__ __launch_bounds__(512, 4) void gemm1_kernel(const bf16* __restrict__ xb,
                                                       const bf16* __restrict__ wgb,
                                                       const bf16* __restrict__ wub,
                                                       bf16* __restrict__ hout,
                                                       const int* __restrict__ counts,
                                                       const int* __restrict__ offsets,
                                                       const int* __restrict__ ptok,
                                                       const float* __restrict__ pprob,
                                                       int* __restrict__ wq) {
    int e = blockIdx.x & 7;
    int cnt = counts[e];
    int hbase = offsets[e];
    int mtiles = (cnt + 127) >> 7;
    int tiles = mtiles * (INTERD / 128);     // mtiles * 11

    __shared__ __align__(16) bf16 smem[3 * 12288];
    __shared__ int s_wi;

    int tid  = threadIdx.x;
    int lane = tid & 63;
    int wid  = tid >> 6;
    int wm   = wid >> 2;              // 0..1  (64-tok stripe)
    int wn   = wid & 3;               // 0..3  (32-inter stripe)

    int srow = tid >> 2;                              // staging row 0..127
    int qs   = (((tid & 3) ^ ((srow >> 1) & 3)) * 8); // swizzled SOURCE chunk (elems)
    int l15  = lane & 15;
    int l4   = lane >> 4;                             // 0..3 (K-chunk)

    // precomputed swizzled LDS read offsets (elements), loop-invariant
    int offA[4], offG[2];
#pragma unroll
    for (int m = 0; m < 4; m++) {
        int r = wm * 64 + m * 16 + l15;
        offA[m] = r * 32 + ((l4 ^ ((r >> 1) & 3)) * 8);
    }
#pragma unroll
    for (int n = 0; n < 2; n++) {
        int r = wn * 32 + n * 16 + l15;
        offG[n] = r * 32 + ((l4 ^ ((r >> 1) & 3)) * 8);
    }

    for (;;) {
        // claim ONE tile per BLOCK, broadcast to all threads
        if (tid == 0) s_wi = atomicAdd(&wq[e], 1);
        __syncthreads();
        int wi = s_wi;
        if (wi >= tiles) break;
        int mt = wi % mtiles;
        int nt = wi / mtiles;
        int m0 = mt * 128;
        int n0 = nt * 128;

        WAIT_VM(0);                   // clean vmcnt (prior stores drained)
        const bf16* gA = xb + (size_t)ptok[e * MAXP + min(m0 + srow, cnt - 1)] * EDIM + qs;
        const bf16* gG = wgb + ((size_t)e * INTERD + n0 + srow) * EDIM + qs;
        const bf16* gU = wub + ((size_t)e * INTERD + n0 + srow) * EDIM + qs;

        f32x4 accg[4][2], accu[4][2];
#pragma unroll
        for (int m = 0; m < 4; m++)
#pragma unroll
            for (int n = 0; n < 2; n++) {
                accg[m][n] = (f32x4){0.f, 0.f, 0.f, 0.f};
                accu[m][n] = (f32x4){0.f, 0.f, 0.f, 0.f};
            }

#define SB1(t) (smem + ((t) % 3) * 12288)
#define G1_STAGE(t) do { bf16* sb_ = SB1(t); int ko_ = (t) * 32; \
        GL16(gA + ko_, sb_ + wid * 512); \
        GL16(gG + ko_, sb_ + 4096 + wid * 512); \
        GL16(gU + ko_, sb_ + 8192 + wid * 512); } while (0)

        G1_STAGE(0); G1_STAGE(1);     // 6 loads in flight

        for (int t = 0; t < 32; ++t) {
            if (t < 30)       { G1_STAGE(t + 2); WAIT_VM(6); }  // tile t landed
            else if (t == 30) { WAIT_VM(3); }
            else              { WAIT_VM(0); }
            BAR();                                   // tile t visible to all waves
            const bf16* sb = SB1(t);
            short8 a_[4], gf[2], uf[2];
#pragma unroll
            for (int m = 0; m < 4; m++) a_[m] = *(const short8*)&sb[offA[m]];
#pragma unroll
            for (int n = 0; n < 2; n++) {
                gf[n] = *(const short8*)&sb[4096 + offG[n]];
                uf[n] = *(const short8*)&sb[8192 + offG[n]];
            }
            PRIO(1);
#pragma unroll
            for (int m = 0; m < 4; m++)
#pragma unroll
                for (int n = 0; n < 2; n++) {
                    accg[m][n] = __builtin_amdgcn_mfma_f32_16x16x32_bf16(a_[m], gf[n], accg[m][n], 0, 0, 0);
                    accu[m][n] = __builtin_amdgcn_mfma_f32_16x16x32_bf16(a_[m], uf[n], accu[m][n], 0, 0, 0);
                }
            PRIO(0);
            BAR();                                   // all reads of tile t done
        }
#undef SB1
#undef G1_STAGE

        // epilogue: h = silu(g) * u * p
#pragma unroll
        for (int m = 0; m < 4; m++)
#pragma unroll
            for (int n = 0; n < 2; n++)
#pragma unroll
                for (int r = 0; r < 4; r++) {
                    int pos = m0 + wm * 64 + m * 16 + l4 * 4 + r;
                    if (pos < cnt) {
                        int col = n0 + wn * 32 + n * 16 + l15;
                        float p = pprob[e * MAXP + pos];
                        float gv = accg[m][n][r];
                        float uv = accu[m][n][r];
                        float hv = (gv / (1.f + __expf(-gv))) * uv * p;
                        hout[(size_t)(hbase + pos) * INTERD + col] = __float2bfloat16(hv);
                    }
                }
    }
}

// ======================= GEMM2: out2[slot] = h[slot] @ wd[e]^T =======================
// Tile 128slot x 256col, BK=32, 44 K-tiles. 8 waves (2M x 4N), wave 64x64.
// LDS: per slot A[128][32] (4096 el) + B[256][32] (8192 el) = 24KB, 3-ring = 72KB
//   -> 2 blocks/CU. Prefetch 2 ahead, vmcnt(6), same swizzle.
// grid: bx = e + 8*(mt + 8*nt), mt<8, nt<4 -> 256 blocks.
__global__ __launch_bounds__(512, 4) void gemm2_kernel(const bf16* __restrict__ h,
                                                       const bf16* __restrict__ wdb,
                                                       float* __restrict__ out2,
                                                       const int* __restrict__ counts,
                                                       const int* __restrict__ offsets) {
    int bx = blockIdx.x;
    int e  = bx & 7;
    int mt = (bx >> 3) & 7;
    int nt = bx >> 6;                 // 0..3
    int cnt = counts[e];
    int n0 = nt * 256;
    int hbase = offsets[e];

    __shared__ __align__(16) bf16 smem[3 * 12288];

    int tid  = threadIdx.x;
    int lane = tid & 63;
    int wid  = tid >> 6;
    int wm   = wid >> 2;              // 0..1 (64-slot stripe)
    int wn   = wid & 3;               // 0..3 (64-col stripe)

    int srow = tid >> 2;                              // 0..127
    int qs   = (((tid & 3) ^ ((srow >> 1) & 3)) * 8);
    int l15  = lane & 15;
    int l4   = lane >> 4;

    int offA[4], offB[4];
#pragma unroll
    for (int m = 0; m < 4; m++) {
        int r = wm * 64 + m * 16 + l15;
        offA[m] = r * 32 + ((l4 ^ ((r >> 1) & 3)) * 8);
    }
#pragma unroll
    for (int n = 0; n < 4; n++) {
        int r = wn * 64 + n * 16 + l15;               // 0..255
        offB[n] = 4096 + r * 32 + ((l4 ^ ((r >> 1) & 3)) * 8);
    }

    const bf16* gB0 = wdb + ((size_t)e * EDIM + n0 + srow) * INTERD + qs;
    const bf16* gB1 = wdb + ((size_t)e * EDIM + n0 + 128 + srow) * INTERD + qs;

    for (int m0 = mt * 128; m0 < cnt; m0 += 1024) {
        WAIT_VM(0);
        const bf16* gA = h + (size_t)(hbase + min(m0 + srow, cnt - 1)) * INTERD + qs;

        f32x4 acc[4][4];
#pragma unroll
        for (int m = 0; m < 4; m++)
#pragma unroll
            for (int n = 0; n < 4; n++) acc[m][n] = (f32x4){0.f, 0.f, 0.f, 0.f};

#define SB2(t) (smem + ((t) % 3) * 12288)
#define G2_STAGE(t) do { bf16* sb_ = SB2(t); int ko_ = (t) * 32; \
        GL16(gA + ko_,  sb_ + wid * 512); \
        GL16(gB0 + ko_, sb_ + 4096 + wid * 512); \
        GL16(gB1 + ko_, sb_ + 8192 + wid * 512); } while (0)

        G2_STAGE(0); G2_STAGE(1);

        for (int t = 0; t < 44; ++t) {
            if (t < 42)       { G2_STAGE(t + 2); WAIT_VM(6); }
            else if (t == 42) { WAIT_VM(3); }
            else              { WAIT_VM(0); }
            BAR();
            const bf16* sb = SB2(t);
            short8 a_[4], b_[4];
#pragma unroll
            for (int m = 0; m < 4; m++) a_[m] = *(const short8*)&sb[offA[m]];
#pragma unroll
            for (int n = 0; n < 4; n++) b_[n] = *(const short8*)&sb[offB[n]];
            PRIO(1);
#pragma unroll
            for (int m = 0; m < 4; m++)
#pragma unroll
                for (int n = 0; n < 4; n++)
                    acc[m][n] = __builtin_amdgcn_mfma_f32_16x16x32_bf16(a_[m], b_[n], acc[m][n], 0, 0, 0);
            PRIO(0);
            BAR();
        }
#undef SB2
#undef G2_STAGE

#pragma unroll
        for (int m = 0; m < 4; m++)
#pragma unroll
            for (int n = 0; n < 4; n++)
#pragma unroll
                for (int r = 0; r < 4; r++) {
                    int pos = m0 + wm * 64 + m * 16 + l4 * 4 + r;
                    if (pos < cnt) {
                        int col = n0 + wn * 64 + n * 16 + l15;
                        out2[(size_t)(hbase + pos) * EDIM + col] = acc[m][n][r];
                    }
                }
    }
}

// ---------------- combine: y[t] = out2[slot0] + out2[slot1] (probs already folded) ---
__global__ __launch_bounds__(256) void combine_kernel(const float* __restrict__ out2,
                                                      const int* __restrict__ inv,
                                                      const int* __restrict__ offsets,
                                                      float* __restrict__ y) {
    int idx = blockIdx.x * 256 + threadIdx.x;   // NTOK*EDIM/4 threads
    int t = idx >> 8;
    int c = (idx & 255) * 4;
    int a = inv[2 * t], b = inv[2 * t + 1];
    size_t sa = (size_t)(offsets[a >> 16] + (a & 0xFFFF)) * EDIM + c;
    size_t sb = (size_t)(offsets[b >> 16] + (b & 0xFFFF)) * EDIM + c;
    float4 va = *(const float4*)(out2 + sa);
    float4 vb = *(const float4*)(out2 + sb);
    float4 o;
    o.x = va.x + vb.x; o.y = va.y + vb.y; o.z = va.z + vb.z; o.w = va.w + vb.w;
    *(float4*)(y + (size_t)t * EDIM + c) = o;
}

// ---------------- launch ----------------
extern "C" void kernel_launch(void* const* d_in, const int* in_sizes, int n_in,
                              void* d_out, int out_size, void* d_ws, size_t ws_size,
                              hipStream_t stream) {
    const float* x      = (const float*)d_in[0];
    const float* gate_w = (const float*)d_in[1];
    const float* wg     = (const float*)d_in[2];
    const float* wu     = (const float*)d_in[3];
    const float* wd     = (const float*)d_in[4];
    float* y = (float*)d_out;

    char* ws = (char*)d_ws;
    constexpr size_t SZ_XB = (size_t)NTOK * EDIM * 2;          // 8 MB
    constexpr size_t SZ_W  = (size_t)WELEM * 2;                // 23.07 MB
    constexpr size_t SZ_H  = (size_t)NTOK * 2 * INTERD * 2;    // 23.07 MB
    bf16* xb  = (bf16*)ws;
    bf16* wgb = (bf16*)(ws + SZ_XB);
    bf16* wub = (bf16*)(ws + SZ_XB + SZ_W);
    bf16* wdb = (bf16*)(ws + SZ_XB + 2 * SZ_W);
    bf16* h   = (bf16*)(ws + SZ_XB + 3 * SZ_W);
    char* meta = ws + SZ_XB + 3 * SZ_W + SZ_H;
    int*   counts  = (int*)meta;
    int*   offsets = (int*)(meta + 256);
    int*   ptok    = (int*)(meta + 512);
    float* pprob   = (float*)(meta + 512 + (size_t)NEXPT * MAXP * 4);
    int*   inv     = (int*)(meta + 512 + (size_t)NEXPT * MAXP * 8);
    int*   wq      = (int*)(meta + 512 + (size_t)NEXPT * MAXP * 8 + (size_t)NTOK * 2 * 4);
    // out2 (8192*1024*4 = 33.6 MB) aliases wgb+wub (46.1 MB), dead after gemm1
    float* out2 = (float*)(ws + SZ_XB);

    hipMemsetAsync(counts, 0, 256, stream);

    cvt3_kernel<<<3072, 256, 0, stream>>>(wg, wgb, wu, wub, wd, wdb);
    router_kernel<<<NTOK, 64, 0, stream>>>(x, gate_w, xb, counts, ptok, pprob, inv);
    scan_kernel<<<1, 64, 0, stream>>>(counts, offsets, wq);

    // 512 blocks, 2/CU; bx&7 = expert -> XCD affinity; dynamic tile queue (per-block)
    gemm1_kernel<<<512, 512, 0, stream>>>(
        xb, wgb, wub, h, counts, offsets, ptok, pprob, wq);
    // bx = e + 8*(mt + 8*nt): 256 blocks
    gemm2_kernel<<<NEXPT * 8 * (EDIM / 256), 512, 0, stream>>>(
        h, wdb, out2, counts, offsets);
    combine_kernel<<<NTOK * EDIM / 4 / 256, 256, 0, stream>>>(out2, inv, offsets, y);
}

// Round 9
// 224.532 us; speedup vs baseline: 1.5164x; 1.2458x over previous
//
#include <hip/hip_runtime.h>
#include <hip/hip_bf16.h>
#include <stdint.h>

typedef __hip_bfloat16 bf16;
typedef __attribute__((ext_vector_type(8))) short short8;
typedef __attribute__((ext_vector_type(4))) float f32x4;

#define NTOK  4096      // B*T
#define EDIM  1024
#define NEXPT 8
#define INTERD 1408
#define MAXP  4096
#define WELEM (NEXPT * INTERD * EDIM)

// async global->LDS, 16B per lane, dest = wave-uniform base + lane*16 (LINEAR)
#define GL16(g, l) __builtin_amdgcn_global_load_lds( \
    (const __attribute__((address_space(1))) unsigned int*)(g), \
    (__attribute__((address_space(3))) unsigned int*)(l), 16, 0, 0)

#define WAIT_VM(n)   asm volatile("s_waitcnt vmcnt(" #n ")" ::: "memory")
#define BAR()        __builtin_amdgcn_s_barrier()
#define PRIO(n)      __builtin_amdgcn_s_setprio(n)

// ---------------- fp32 -> bf16 conversion for the 3 weight tensors ----------------
__global__ __launch_bounds__(256) void cvt3_kernel(const float* __restrict__ wg, bf16* __restrict__ wgb,
                                                   const float* __restrict__ wu, bf16* __restrict__ wub,
                                                   const float* __restrict__ wd, bf16* __restrict__ wdb) {
    const float* src; bf16* dst; int b = blockIdx.x;
    if (b < 1024)      { src = wg; dst = wgb; }
    else if (b < 2048) { src = wu; dst = wub; b -= 1024; }
    else               { src = wd; dst = wdb; b -= 2048; }
    int n = WELEM;
    int i = (b * 256 + threadIdx.x) * 4;
    int stride = 1024 * 256 * 4;
    for (; i < n; i += stride) {
        float4 v = *(const float4*)(src + i);
        ushort4 o; bf16 t;
        t = __float2bfloat16(v.x); o.x = *(unsigned short*)&t;
        t = __float2bfloat16(v.y); o.y = *(unsigned short*)&t;
        t = __float2bfloat16(v.z); o.z = *(unsigned short*)&t;
        t = __float2bfloat16(v.w); o.w = *(unsigned short*)&t;
        *(ushort4*)(dst + i) = o;
    }
}

// ------- router: scores (fp64-exact) -> top2 + probs; x->bf16. NO ATOMICS. ---------
// 4 waves/block, one token per wave. Writes sel[t] = e0 | (e1<<8), tprob[2t],[2t+1].
__global__ __launch_bounds__(256) void router_kernel(const float* __restrict__ x,
                                                     const float* __restrict__ gw,
                                                     bf16* __restrict__ xb,
                                                     int* __restrict__ sel,
                                                     float* __restrict__ tprob) {
    int t = blockIdx.x * 4 + (threadIdx.x >> 6);
    int lane = threadIdx.x & 63;
    const float* xr = x + (size_t)t * EDIM;

    // each lane owns d in [lane*16, lane*16+16)
    float xv[16];
#pragma unroll
    for (int j = 0; j < 4; j++) {
        float4 v = *(const float4*)(xr + lane * 16 + j * 4);
        xv[4 * j] = v.x; xv[4 * j + 1] = v.y; xv[4 * j + 2] = v.z; xv[4 * j + 3] = v.w;
    }
    // fused x -> bf16 store
    bf16* xbr = xb + (size_t)t * EDIM;
#pragma unroll
    for (int j = 0; j < 4; j++) {
        ushort4 o; bf16 c;
        c = __float2bfloat16(xv[4 * j]);     o.x = *(unsigned short*)&c;
        c = __float2bfloat16(xv[4 * j + 1]); o.y = *(unsigned short*)&c;
        c = __float2bfloat16(xv[4 * j + 2]); o.z = *(unsigned short*)&c;
        c = __float2bfloat16(xv[4 * j + 3]); o.w = *(unsigned short*)&c;
        *(ushort4*)(xbr + lane * 16 + j * 4) = o;
    }

    double acc[NEXPT];
#pragma unroll
    for (int e = 0; e < NEXPT; e++) acc[e] = 0.0;
#pragma unroll
    for (int e = 0; e < NEXPT; e++) {
        const float* gr = gw + e * EDIM + lane * 16;
#pragma unroll
        for (int j = 0; j < 16; j++) acc[e] += (double)xv[j] * (double)gr[j];
    }
#pragma unroll
    for (int off = 32; off >= 1; off >>= 1) {
#pragma unroll
        for (int e = 0; e < NEXPT; e++) acc[e] += __shfl_xor(acc[e], off, 64);
    }
    if (lane == 0) {
        int e0 = 0; double s0 = acc[0];
        for (int e = 1; e < NEXPT; e++) if (acc[e] > s0) { s0 = acc[e]; e0 = e; }
        int e1 = -1; double s1 = -1e300;
        for (int e = 0; e < NEXPT; e++) if (e != e0 && acc[e] > s1) { s1 = acc[e]; e1 = e; }
        float z = __expf((float)(s1 - s0));
        float p0 = 1.f / (1.f + z);
        sel[t] = e0 | (e1 << 8);
        tprob[2 * t] = p0;
        tprob[2 * t + 1] = 1.f - p0;
    }
}

// ------- bucket: stable counting-sort of (token,slot) into expert buckets ----------
// ONE block, 8 waves; wave w owns expert w. Deterministic, atomic-free.
__global__ __launch_bounds__(512) void bucket_kernel(const int* __restrict__ sel,
                                                     const float* __restrict__ tprob,
                                                     int* __restrict__ counts,
                                                     int* __restrict__ offsets,
                                                     int* __restrict__ ptok,
                                                     float* __restrict__ pprob,
                                                     int* __restrict__ inv,
                                                     int* __restrict__ wq) {
    __shared__ int scnt[NEXPT];
    int w = threadIdx.x >> 6;         // expert owned by this wave
    int lane = threadIdx.x & 63;
    unsigned long long ltmask = (lane == 63) ? ~0ull >> 1 : (1ull << lane) - 1;
    int base = 0;
    for (int t0 = 0; t0 < NTOK; t0 += 64) {
        int t = t0 + lane;
        int s = sel[t];
        int e0 = s & 0xff, e1 = (s >> 8) & 0xff;
        unsigned long long m0 = __ballot(e0 == w);
        if (e0 == w) {
            int pos = base + __popcll(m0 & ltmask);
            ptok[w * MAXP + pos] = t;
            pprob[w * MAXP + pos] = tprob[2 * t];
            inv[2 * t] = (w << 16) | pos;
        }
        base += __popcll(m0);
        unsigned long long m1 = __ballot(e1 == w);
        if (e1 == w) {
            int pos = base + __popcll(m1 & ltmask);
            ptok[w * MAXP + pos] = t;
            pprob[w * MAXP + pos] = tprob[2 * t + 1];
            inv[2 * t + 1] = (w << 16) | pos;
        }
        base += __popcll(m1);
    }
    if (lane == 0) scnt[w] = base;
    __syncthreads();
    if (threadIdx.x < NEXPT) {
        int off = 0;
        for (int e = 0; e < (int)threadIdx.x; e++) off += scnt[e];
        counts[threadIdx.x] = scnt[threadIdx.x];
        offsets[threadIdx.x] = off;
        wq[threadIdx.x] = 0;
    }
}

// ======================= GEMM1: h = p * silu(x@wg^T) * (x@wu^T) =======================
// Tile 128tok x 128inter, BK=32, 32 K-tiles. 8 waves (2M x 4N), wave 64x32 on g AND u.
// LDS: 3-slot ring 72KB -> 2 blocks/CU. Prefetch 2 ahead, counted vmcnt(6), XOR swizzle.
// Dynamic per-expert queue claimed once per block; bx&7 = expert -> XCD affinity.
__global__ __launch_bounds__(512, 4) void gemm1_kernel(const bf16* __restrict__ xb,
                                                       const bf16* __restrict__ wgb,
                                                       const bf16* __restrict__ wub,
                                                       bf16* __restrict__ hout,
                                                       const int* __restrict__ counts,
                                                       const int* __restrict__ offsets,
                                                       const int* __restrict__ ptok,
                                                       const float* __restrict__ pprob,
                                                       int* __restrict__ wq) {
    int e = blockIdx.x & 7;
    int cnt = counts[e];
    int hbase = offsets[e];
    int mtiles = (cnt + 127) >> 7;
    int tiles = mtiles * (INTERD / 128);     // mtiles * 11

    __shared__ __align__(16) bf16 smem[3 * 12288];
    __shared__ int s_wi;

    int tid  = threadIdx.x;
    int lane = tid & 63;
    int wid  = tid >> 6;
    int wm   = wid >> 2;              // 0..1  (64-tok stripe)
    int wn   = wid & 3;               // 0..3  (32-inter stripe)

    int srow = tid >> 2;                              // staging row 0..127
    int qs   = (((tid & 3) ^ ((srow >> 1) & 3)) * 8); // swizzled SOURCE chunk (elems)
    int l15  = lane & 15;
    int l4   = lane >> 4;                             // 0..3 (K-chunk)

    int offA[4], offG[2];
#pragma unroll
    for (int m = 0; m < 4; m++) {
        int r = wm * 64 + m * 16 + l15;
        offA[m] = r * 32 + ((l4 ^ ((r >> 1) & 3)) * 8);
    }
#pragma unroll
    for (int n = 0; n < 2; n++) {
        int r = wn * 32 + n * 16 + l15;
        offG[n] = r * 32 + ((l4 ^ ((r >> 1) & 3)) * 8);
    }

    for (;;) {
        if (tid == 0) s_wi = atomicAdd(&wq[e], 1);
        __syncthreads();
        int wi = s_wi;
        if (wi >= tiles) break;
        int mt = wi % mtiles;
        int nt = wi / mtiles;
        int m0 = mt * 128;
        int n0 = nt * 128;

        WAIT_VM(0);                   // clean vmcnt (prior stores drained)
        const bf16* gA = xb + (size_t)ptok[e * MAXP + min(m0 + srow, cnt - 1)] * EDIM + qs;
        const bf16* gG = wgb + ((size_t)e * INTERD + n0 + srow) * EDIM + qs;
        const bf16* gU = wub + ((size_t)e * INTERD + n0 + srow) * EDIM + qs;

        f32x4 accg[4][2], accu[4][2];
#pragma unroll
        for (int m = 0; m < 4; m++)
#pragma unroll
            for (int n = 0; n < 2; n++) {
                accg[m][n] = (f32x4){0.f, 0.f, 0.f, 0.f};
                accu[m][n] = (f32x4){0.f, 0.f, 0.f, 0.f};
            }

#define SB1(t) (smem + ((t) % 3) * 12288)
#define G1_STAGE(t) do { bf16* sb_ = SB1(t); int ko_ = (t) * 32; \
        GL16(gA + ko_, sb_ + wid * 512); \
        GL16(gG + ko_, sb_ + 4096 + wid * 512); \
        GL16(gU + ko_, sb_ + 8192 + wid * 512); } while (0)

        G1_STAGE(0); G1_STAGE(1);     // 6 loads in flight

        for (int t = 0; t < 32; ++t) {
            if (t < 30)       { G1_STAGE(t + 2); WAIT_VM(6); }  // tile t landed
            else if (t == 30) { WAIT_VM(3); }
            else              { WAIT_VM(0); }
            BAR();                                   // tile t visible to all waves
            const bf16* sb = SB1(t);
            short8 a_[4], gf[2], uf[2];
#pragma unroll
            for (int m = 0; m < 4; m++) a_[m] = *(const short8*)&sb[offA[m]];
#pragma unroll
            for (int n = 0; n < 2; n++) {
                gf[n] = *(const short8*)&sb[4096 + offG[n]];
                uf[n] = *(const short8*)&sb[8192 + offG[n]];
            }
            PRIO(1);
#pragma unroll
            for (int m = 0; m < 4; m++)
#pragma unroll
                for (int n = 0; n < 2; n++) {
                    accg[m][n] = __builtin_amdgcn_mfma_f32_16x16x32_bf16(a_[m], gf[n], accg[m][n], 0, 0, 0);
                    accu[m][n] = __builtin_amdgcn_mfma_f32_16x16x32_bf16(a_[m], uf[n], accu[m][n], 0, 0, 0);
                }
            PRIO(0);
            BAR();                                   // all reads of tile t done
        }
#undef SB1
#undef G1_STAGE

        // epilogue: h = silu(g) * u * p
#pragma unroll
        for (int m = 0; m < 4; m++)
#pragma unroll
            for (int n = 0; n < 2; n++)
#pragma unroll
                for (int r = 0; r < 4; r++) {
                    int pos = m0 + wm * 64 + m * 16 + l4 * 4 + r;
                    if (pos < cnt) {
                        int col = n0 + wn * 32 + n * 16 + l15;
                        float p = pprob[e * MAXP + pos];
                        float gv = accg[m][n][r];
                        float uv = accu[m][n][r];
                        float hv = (gv / (1.f + __expf(-gv))) * uv * p;
                        hout[(size_t)(hbase + pos) * INTERD + col] = __float2bfloat16(hv);
                    }
                }
    }
}

// ======================= GEMM2: out2[slot] = h[slot] @ wd[e]^T =======================
// Tile 128slot x 256col, BK=32, 44 K-tiles. 8 waves (2M x 4N), wave 64x64.
// LDS 3-ring 72KB -> 2 blocks/CU. Prefetch 2 ahead, vmcnt(6), same swizzle.
// grid: bx = e + 8*(mt + 8*nt), mt<8, nt<4 -> 256 blocks.
__global__ __launch_bounds__(512, 4) void gemm2_kernel(const bf16* __restrict__ h,
                                                       const bf16* __restrict__ wdb,
                                                       float* __restrict__ out2,
                                                       const int* __restrict__ counts,
                                                       const int* __restrict__ offsets) {
    int bx = blockIdx.x;
    int e  = bx & 7;
    int mt = (bx >> 3) & 7;
    int nt = bx >> 6;                 // 0..3
    int cnt = counts[e];
    int n0 = nt * 256;
    int hbase = offsets[e];

    __shared__ __align__(16) bf16 smem[3 * 12288];

    int tid  = threadIdx.x;
    int lane = tid & 63;
    int wid  = tid >> 6;
    int wm   = wid >> 2;              // 0..1 (64-slot stripe)
    int wn   = wid & 3;               // 0..3 (64-col stripe)

    int srow = tid >> 2;                              // 0..127
    int qs   = (((tid & 3) ^ ((srow >> 1) & 3)) * 8);
    int l15  = lane & 15;
    int l4   = lane >> 4;

    int offA[4], offB[4];
#pragma unroll
    for (int m = 0; m < 4; m++) {
        int r = wm * 64 + m * 16 + l15;
        offA[m] = r * 32 + ((l4 ^ ((r >> 1) & 3)) * 8);
    }
#pragma unroll
    for (int n = 0; n < 4; n++) {
        int r = wn * 64 + n * 16 + l15;               // 0..255
        offB[n] = 4096 + r * 32 + ((l4 ^ ((r >> 1) & 3)) * 8);
    }

    const bf16* gB0 = wdb + ((size_t)e * EDIM + n0 + srow) * INTERD + qs;
    const bf16* gB1 = wdb + ((size_t)e * EDIM + n0 + 128 + srow) * INTERD + qs;

    for (int m0 = mt * 128; m0 < cnt; m0 += 1024) {
        WAIT_VM(0);
        const bf16* gA = h + (size_t)(hbase + min(m0 + srow, cnt - 1)) * INTERD + qs;

        f32x4 acc[4][4];
#pragma unroll
        for (int m = 0; m < 4; m++)
#pragma unroll
            for (int n = 0; n < 4; n++) acc[m][n] = (f32x4){0.f, 0.f, 0.f, 0.f};

#define SB2(t) (smem + ((t) % 3) * 12288)
#define G2_STAGE(t) do { bf16* sb_ = SB2(t); int ko_ = (t) * 32; \
        GL16(gA + ko_,  sb_ + wid * 512); \
        GL16(gB0 + ko_, sb_ + 4096 + wid * 512); \
        GL16(gB1 + ko_, sb_ + 8192 + wid * 512); } while (0)

        G2_STAGE(0); G2_STAGE(1);

        for (int t = 0; t < 44; ++t) {
            if (t < 42)       { G2_STAGE(t + 2); WAIT_VM(6); }
            else if (t == 42) { WAIT_VM(3); }
            else              { WAIT_VM(0); }
            BAR();
            const bf16* sb = SB2(t);
            short8 a_[4], b_[4];
#pragma unroll
            for (int m = 0; m < 4; m++) a_[m] = *(const short8*)&sb[offA[m]];
#pragma unroll
            for (int n = 0; n < 4; n++) b_[n] = *(const short8*)&sb[offB[n]];
            PRIO(1);
#pragma unroll
            for (int m = 0; m < 4; m++)
#pragma unroll
                for (int n = 0; n < 4; n++)
                    acc[m][n] = __builtin_amdgcn_mfma_f32_16x16x32_bf16(a_[m], b_[n], acc[m][n], 0, 0, 0);
            PRIO(0);
            BAR();
        }
#undef SB2
#undef G2_STAGE

#pragma unroll
        for (int m = 0; m < 4; m++)
#pragma unroll
            for (int n = 0; n < 4; n++)
#pragma unroll
                for (int r = 0; r < 4; r++) {
                    int pos = m0 + wm * 64 + m * 16 + l4 * 4 + r;
                    if (pos < cnt) {
                        int col = n0 + wn * 64 + n * 16 + l15;
                        out2[(size_t)(hbase + pos) * EDIM + col] = acc[m][n][r];
                    }
                }
    }
}

// ---------------- combine: y[t] = out2[slot0] + out2[slot1] (probs already folded) ---
__global__ __launch_bounds__(256) void combine_kernel(const float* __restrict__ out2,
                                                      const int* __restrict__ inv,
                                                      const int* __restrict__ offsets,
                                                      float* __restrict__ y) {
    int idx = blockIdx.x * 256 + threadIdx.x;   // NTOK*EDIM/4 threads
    int t = idx >> 8;
    int c = (idx & 255) * 4;
    int a = inv[2 * t], b = inv[2 * t + 1];
    size_t sa = (size_t)(offsets[a >> 16] + (a & 0xFFFF)) * EDIM + c;
    size_t sb = (size_t)(offsets[b >> 16] + (b & 0xFFFF)) * EDIM + c;
    float4 va = *(const float4*)(out2 + sa);
    float4 vb = *(const float4*)(out2 + sb);
    float4 o;
    o.x = va.x + vb.x; o.y = va.y + vb.y; o.z = va.z + vb.z; o.w = va.w + vb.w;
    *(float4*)(y + (size_t)t * EDIM + c) = o;
}

// ---------------- launch ----------------
extern "C" void kernel_launch(void* const* d_in, const int* in_sizes, int n_in,
                              void* d_out, int out_size, void* d_ws, size_t ws_size,
                              hipStream_t stream) {
    const float* x      = (const float*)d_in[0];
    const float* gate_w = (const float*)d_in[1];
    const float* wg     = (const float*)d_in[2];
    const float* wu     = (const float*)d_in[3];
    const float* wd     = (const float*)d_in[4];
    float* y = (float*)d_out;

    char* ws = (char*)d_ws;
    constexpr size_t SZ_XB = (size_t)NTOK * EDIM * 2;          // 8 MB
    constexpr size_t SZ_W  = (size_t)WELEM * 2;                // 23.07 MB
    constexpr size_t SZ_H  = (size_t)NTOK * 2 * INTERD * 2;    // 23.07 MB
    bf16* xb  = (bf16*)ws;
    bf16* wgb = (bf16*)(ws + SZ_XB);
    bf16* wub = (bf16*)(ws + SZ_XB + SZ_W);
    bf16* wdb = (bf16*)(ws + SZ_XB + 2 * SZ_W);
    bf16* h   = (bf16*)(ws + SZ_XB + 3 * SZ_W);
    char* meta = ws + SZ_XB + 3 * SZ_W + SZ_H;
    int*   counts  = (int*)meta;
    int*   offsets = (int*)(meta + 256);
    int*   ptok    = (int*)(meta + 512);
    float* pprob   = (float*)(meta + 512 + (size_t)NEXPT * MAXP * 4);
    int*   inv     = (int*)(meta + 512 + (size_t)NEXPT * MAXP * 8);
    int*   wq      = (int*)(meta + 512 + (size_t)NEXPT * MAXP * 8 + (size_t)NTOK * 2 * 4);
    int*   sel     = (int*)(meta + 512 + (size_t)NEXPT * MAXP * 8 + (size_t)NTOK * 2 * 4 + 256);
    float* tprob   = (float*)((char*)sel + (size_t)NTOK * 4);
    // out2 (8192*1024*4 = 33.6 MB) aliases wgb+wub (46.1 MB), dead after gemm1
    float* out2 = (float*)(ws + SZ_XB);

    cvt3_kernel<<<3072, 256, 0, stream>>>(wg, wgb, wu, wub, wd, wdb);
    router_kernel<<<NTOK / 4, 256, 0, stream>>>(x, gate_w, xb, sel, tprob);
    bucket_kernel<<<1, 512, 0, stream>>>(sel, tprob, counts, offsets, ptok, pprob, inv, wq);

    // 512 blocks, 2/CU; bx&7 = expert -> XCD affinity; dynamic tile queue (per-block)
    gemm1_kernel<<<512, 512, 0, stream>>>(
        xb, wgb, wub, h, counts, offsets, ptok, pprob, wq);
    // bx = e + 8*(mt + 8*nt): 256 blocks
    gemm2_kernel<<<NEXPT * 8 * (EDIM / 256), 512, 0, stream>>>(
        h, wdb, out2, counts, offsets);
    combine_kernel<<<NTOK * EDIM / 4 / 256, 256, 0, stream>>>(out2, inv, offsets, y);
}